// Round 5
// baseline (477.460 us; speedup 1.0000x reference)
//
#include <hip/hip_runtime.h>

// Graph_CNN_ortega — pure-bf16 MFMA. Big GEMMs (AGG, OUT) on a counted-vmcnt
// ring-3 256x128 kernel with m201-style 2-phase-per-K-tile interleave
// (T3+T4+T2+T5+T1). MLP1+MLP2 fused into one kernel (M1 lives in LDS only).
// B=64, N=1024, DIN=64, DH=128, H_MLP=128, L=3, C=4.

typedef unsigned short u16;
typedef short bf16x8 __attribute__((ext_vector_type(8)));
typedef float f32x4 __attribute__((ext_vector_type(4)));
typedef u16 u16x4 __attribute__((ext_vector_type(4)));

__device__ __forceinline__ u16 f2bf(float x){
  unsigned u = __builtin_bit_cast(unsigned, x);
  u += 0x7fffu + ((u >> 16) & 1u);          // RNE
  return (u16)(u >> 16);
}
__device__ __forceinline__ float bf2f(u16 h){
  return __builtin_bit_cast(float, ((unsigned)h) << 16);
}
__device__ __forceinline__ void gload16(const u16* g, u16* l){
  __builtin_amdgcn_global_load_lds(
      (const __attribute__((address_space(1))) unsigned int*)(g),
      (__attribute__((address_space(3))) unsigned int*)(l), 16, 0, 0);
}

// ---------------- preprocessing ----------------

__global__ void prep_weights(const float* __restrict__ w1_0, const float* __restrict__ w2_0,
                             const float* __restrict__ w1_r, const float* __restrict__ w2_r,
                             const float* __restrict__ bw,
                             u16* __restrict__ W1T0, u16* __restrict__ W2T0,
                             u16* __restrict__ W1Tr, u16* __restrict__ W2Tr,
                             float* __restrict__ wsb){
  int id = blockIdx.x*256 + threadIdx.x;
  if (id < 3){
    float a0=bw[id*3+0], a1=bw[id*3+1], a2=bw[id*3+2];
    float m = fmaxf(a0,fmaxf(a1,a2));
    float e0=expf(a0-m), e1=expf(a1-m), e2=expf(a2-m);
    float s = e0+e1+e2;
    wsb[id*3+0]=e0/s; wsb[id*3+1]=e1/s; wsb[id*3+2]=e2/s;
  }
  if (id < 24576){                       // W1T0[k][h][d]=w1_0[k][d][h], d<64
    int k=id/8192, rem=id%8192, h=rem/64, d=rem%64;
    W1T0[id] = f2bf(w1_0[(k*64+d)*128 + h]);
  } else if (id < 73728){                // W2T0[k][o][h]=w2_0[k][h][o]
    int t=id-24576, k=t/16384, rem=t%16384, o=rem/128, h=rem%128;
    W2T0[t] = f2bf(w2_0[(k*128+h)*128 + o]);
  } else if (id < 172032){               // W1Tr[lk][h][d]=w1_r[lk][d][h]
    int t=id-73728, lk=t/16384, rem=t%16384, h=rem/128, d=rem%128;
    W1Tr[t] = f2bf(w1_r[lk*16384 + d*128 + h]);
  } else if (id < 270336){               // W2Tr[lk][o][h]=w2_r[lk][h][o]
    int t=id-172032, lk=t/16384, rem=t%16384, o=rem/128, h=rem%128;
    W2Tr[t] = f2bf(w2_r[lk*16384 + h*128 + o]);
  }
}

// U[3][1024][1024] f32 -> UTcat[k][i][j]=U[k][j][i] and Ucat[i][k*1024+j]
__global__ void prep_U(const float* __restrict__ U, u16* __restrict__ UTcat,
                       u16* __restrict__ Ucat){
  __shared__ float t[32][33];
  int k = blockIdx.z, i0 = blockIdx.x*32, j0 = blockIdx.y*32;
  size_t kb = (size_t)k << 20;
  #pragma unroll
  for (int rr=0; rr<4; rr++){
    int r = threadIdx.y*4+rr, c = threadIdx.x;
    float v = U[kb + (size_t)(j0+r)*1024 + i0+c];
    t[r][c] = v;
    Ucat[(size_t)(j0+r)*3072 + k*1024 + i0+c] = f2bf(v);
  }
  __syncthreads();
  #pragma unroll
  for (int rr=0; rr<4; rr++){
    int r = threadIdx.y*4+rr, c = threadIdx.x;
    UTcat[kb + (size_t)(i0+r)*1024 + j0+c] = f2bf(t[c][r]);
  }
}

// x[b][j][d] -> HT0[(b*64+d)][j] bf16
__global__ void prep_x(const float* __restrict__ x, u16* __restrict__ H){
  __shared__ float t[32][33];
  int b = blockIdx.z, d0 = blockIdx.x*32, j0 = blockIdx.y*32;
  #pragma unroll
  for (int rr=0;rr<4;rr++){
    int r=threadIdx.y*4+rr, c=threadIdx.x;
    t[r][c] = x[((size_t)b*1024 + j0+r)*64 + d0+c];
  }
  __syncthreads();
  #pragma unroll
  for (int rr=0;rr<4;rr++){
    int r=threadIdx.y*4+rr, c=threadIdx.x;
    H[(size_t)(b*64 + d0+r)*1024 + j0+c] = f2bf(t[c][r]);
  }
}

// ---------------- big NT GEMM: 256x128 tile, BK=64, ring-3 LDS, counted vmcnt,
// 2 phases per K-tile: {8 ds_read | half-stage(t+2) | bar | prio MFMA x16 | bar}.
// REORD=0: C[z*cRowZ + m][n].  REORD=p: col n=(b,d), Din=2^p; writes
// C[((z*64+b)*1024+m)][d] (AGG2 row order (k,b,j)).
template<bool RELU, int REORD>
__global__ __launch_bounds__(512)
void gemm_big(const u16* __restrict__ A, const u16* __restrict__ B,
              u16* __restrict__ C, int Nc, int K, long aZ, int cRowZ)
{
  __shared__ __align__(16) u16 ldsA[3*16384];   // 3 x [256][64]  (96 KB)
  __shared__ __align__(16) u16 ldsB[3*8192];    // 3 x [128][64]  (48 KB)
  const int tid = threadIdx.x;
  const int z = blockIdx.z;
  const u16* Ab = A + (size_t)z*aZ;
  const int gx = gridDim.x;
  const int nwg = gx*gridDim.y;
  int flat = blockIdx.y*gx + blockIdx.x;
  if ((nwg & 7) == 0) flat = (flat & 7)*(nwg >> 3) + (flat >> 3);  // T1 XCD swizzle
  const int bm = (flat/gx)*256, bn = (flat%gx)*128;
  const int wave = tid>>6, lane = tid&63;
  const int wm = (wave&3)*64, wn = (wave>>2)*64;
  const int rl = lane&15, ksb = lane>>4;
  const int xr = (rl&7)<<3;                      // ds_read swizzle (u16 elems)
  const int srow = tid>>3;                       // stage: row within 64-row chunk
  const int scol = ((tid&7)*8) ^ ((srow&7)<<3);  // stage: pre-swizzled src col
  const int NT = K>>6;

  f32x4 acc[4][4];
  #pragma unroll
  for (int mi=0;mi<4;mi++)
    #pragma unroll
    for (int ni=0;ni<4;ni++){ f32x4 zv={0.f,0.f,0.f,0.f}; acc[mi][ni]=zv; }

  auto stageA = [&](int t){
    const int sa = (t%3)*16384;
    const int k0 = t<<6;
    #pragma unroll
    for (int c=0;c<4;c++){
      const int row = c*64 + srow;
      gload16(Ab + (size_t)(bm+row)*K + k0 + scol, &ldsA[sa + c*4096 + tid*8]);
    }
  };
  auto stageB = [&](int t){
    const int sb = (t%3)*8192;
    const int k0 = t<<6;
    #pragma unroll
    for (int c=0;c<2;c++){
      const int row = c*64 + srow;
      gload16(B + (size_t)(bn+row)*K + k0 + scol, &ldsB[sb + c*4096 + tid*8]);
    }
  };

  stageA(0); stageB(0); stageA(1); stageB(1);
  asm volatile("s_waitcnt vmcnt(6)" ::: "memory");   // tile 0 fully landed
  __builtin_amdgcn_s_barrier();
  __builtin_amdgcn_sched_barrier(0);

  for (int t=0; t<NT; t++){
    const int sa = (t%3)*16384, sb = (t%3)*8192;
    // ---- phase 1: kk=0 fragments + A-half of stage(t+2)
    bf16x8 a0[4], b0[4];
    #pragma unroll
    for (int mi=0;mi<4;mi++)
      a0[mi] = *(const bf16x8*)&ldsA[sa + (wm+mi*16+rl)*64 + ((ksb*8) ^ xr)];
    #pragma unroll
    for (int ni=0;ni<4;ni++)
      b0[ni] = *(const bf16x8*)&ldsB[sb + (wn+ni*16+rl)*64 + ((ksb*8) ^ xr)];
    if (t+2 < NT) stageA(t+2);
    __builtin_amdgcn_s_barrier();
    __builtin_amdgcn_sched_barrier(0);
    __builtin_amdgcn_s_setprio(1);
    #pragma unroll
    for (int ni=0;ni<4;ni++)
      #pragma unroll
      for (int mi=0;mi<4;mi++)
        acc[mi][ni] = __builtin_amdgcn_mfma_f32_16x16x32_bf16(a0[mi], b0[ni], acc[mi][ni], 0,0,0);
    __builtin_amdgcn_s_setprio(0);
    __builtin_amdgcn_s_barrier();
    __builtin_amdgcn_sched_barrier(0);
    // ---- phase 2: kk=1 fragments + B-half of stage(t+2)
    bf16x8 a1[4], b1v[4];
    #pragma unroll
    for (int mi=0;mi<4;mi++)
      a1[mi] = *(const bf16x8*)&ldsA[sa + (wm+mi*16+rl)*64 + ((32 + ksb*8) ^ xr)];
    #pragma unroll
    for (int ni=0;ni<4;ni++)
      b1v[ni] = *(const bf16x8*)&ldsB[sb + (wn+ni*16+rl)*64 + ((32 + ksb*8) ^ xr)];
    if (t+2 < NT) stageB(t+2);
    __builtin_amdgcn_s_barrier();
    __builtin_amdgcn_sched_barrier(0);
    __builtin_amdgcn_s_setprio(1);
    #pragma unroll
    for (int ni=0;ni<4;ni++)
      #pragma unroll
      for (int mi=0;mi<4;mi++)
        acc[mi][ni] = __builtin_amdgcn_mfma_f32_16x16x32_bf16(a1[mi], b1v[ni], acc[mi][ni], 0,0,0);
    __builtin_amdgcn_s_setprio(0);
    if (t+2 < NT)      asm volatile("s_waitcnt vmcnt(6)" ::: "memory");
    else if (t+1 < NT) asm volatile("s_waitcnt vmcnt(0)" ::: "memory");
    __builtin_amdgcn_s_barrier();
    __builtin_amdgcn_sched_barrier(0);
  }

  #pragma unroll
  for (int ni=0;ni<4;ni++){
    const int col = bn + wn + ni*16 + rl;
    #pragma unroll
    for (int mi=0;mi<4;mi++){
      const int row0 = bm + wm + mi*16 + ksb*4;          // m89 C layout
      #pragma unroll
      for (int r=0;r<4;r++){
        float v = acc[mi][ni][r];
        if (RELU) v = fmaxf(v, 0.f);
        if constexpr (REORD){
          const int Din = 1 << REORD;
          const int bb = col >> REORD, d = col & (Din-1);
          C[((size_t)((z<<6) + bb)*1024 + row0 + r)*Din + d] = f2bf(v);
        } else {
          C[(size_t)(z*cRowZ + row0 + r)*Nc + col] = f2bf(v);
        }
      }
    }
  }
}

// ---------------- fused MLP: M1 never leaves LDS ----------------
// Block = (k,b,jt): 128 j-rows. stage1: M1=relu(AGG2@W1T^T + b1) -> LDS;
// stage2: M2T[(b,o)][(k,j)] = (W2T@M1^T + b2)*ws_k. All LDS XOR-swizzled
// (elem ^= (row&7)<<3); staged via gload16 with pre-swizzled global source.
template<int DIN>
__global__ __launch_bounds__(256)
void fused_mlp(const u16* __restrict__ AGG, const u16* __restrict__ W1T,
               const u16* __restrict__ W2T, const float* __restrict__ b1g,
               const float* __restrict__ b2g, const float* __restrict__ wsl,
               u16* __restrict__ M2T)
{
  constexpr int JW1 = 128*DIN;                 // elems of lJ / lW1
  __shared__ __align__(16) u16 lds[2*JW1 + 16384]; // lJ | lW1 | lW2 ; lM1 @0
  const int tid = threadIdx.x;
  const int jt = blockIdx.x, z = blockIdx.z, k = z>>6, b = z&63;
  const u16* Ag  = AGG + ((size_t)z*1024 + jt*128)*DIN;
  const u16* W1k = W1T + k*JW1;
  const u16* W2k = W2T + k*16384;
  const int wave = tid>>6, lane = tid&63;
  const int wm = (wave>>1)*64, wn = (wave&1)*64;
  const int rl = lane&15, ksb = lane>>4;
  const int xr = (rl&7)<<3;

  constexpr int CJ = JW1/2048;                 // gload16s per thread (4 or 8)
  #pragma unroll
  for (int c=0;c<CJ;c++){
    const int e = c*2048 + tid*8, row = e/DIN, col = e%DIN;
    gload16(Ag + (size_t)row*DIN + (col ^ ((row&7)<<3)), &lds[e]);
  }
  #pragma unroll
  for (int c=0;c<CJ;c++){
    const int e = c*2048 + tid*8, row = e/DIN, col = e%DIN;
    gload16(W1k + (size_t)row*DIN + (col ^ ((row&7)<<3)), &lds[JW1 + e]);
  }
  #pragma unroll
  for (int c=0;c<8;c++){
    const int e = c*2048 + tid*8, row = e>>7, col = e&127;
    gload16(W2k + (size_t)row*128 + (col ^ ((row&7)<<3)), &lds[2*JW1 + e]);
  }
  asm volatile("s_waitcnt vmcnt(8)" ::: "memory");   // lJ + lW1 landed
  __builtin_amdgcn_s_barrier();
  __builtin_amdgcn_sched_barrier(0);

  // stage 1: C[j][h] = sum_d AGG[j][d]*W1T[h][d]
  f32x4 acc[4][4];
  #pragma unroll
  for (int mi=0;mi<4;mi++)
    #pragma unroll
    for (int ni=0;ni<4;ni++){ f32x4 zv={0.f,0.f,0.f,0.f}; acc[mi][ni]=zv; }
  #pragma unroll
  for (int k0=0; k0<DIN; k0+=32){
    bf16x8 aj[4], wh[4];
    #pragma unroll
    for (int mi=0;mi<4;mi++)
      aj[mi] = *(const bf16x8*)&lds[(wm+mi*16+rl)*DIN + ((k0+ksb*8) ^ xr)];
    #pragma unroll
    for (int ni=0;ni<4;ni++)
      wh[ni] = *(const bf16x8*)&lds[JW1 + (wn+ni*16+rl)*DIN + ((k0+ksb*8) ^ xr)];
    #pragma unroll
    for (int ni=0;ni<4;ni++)
      #pragma unroll
      for (int mi=0;mi<4;mi++)
        acc[mi][ni] = __builtin_amdgcn_mfma_f32_16x16x32_bf16(aj[mi], wh[ni], acc[mi][ni], 0,0,0);
  }
  __syncthreads();                              // lJ/lW1 reads done everywhere

  float bh[4];
  #pragma unroll
  for (int ni=0;ni<4;ni++) bh[ni] = b1g[k*128 + wn + ni*16 + rl];
  #pragma unroll
  for (int ni=0;ni<4;ni++){
    const int h = wn + ni*16 + rl;
    #pragma unroll
    for (int mi=0;mi<4;mi++){
      #pragma unroll
      for (int r=0;r<4;r++){
        const int j = wm + mi*16 + ksb*4 + r;
        const float v = fmaxf(acc[mi][ni][r] + bh[ni], 0.f);
        lds[j*128 + (h ^ ((j&7)<<3))] = f2bf(v);   // lM1 @0
      }
    }
  }
  __syncthreads();                              // M1 visible; lW2 landed

  // stage 2: C2[o][j] = sum_h W2T[o][h]*M1[j][h]
  f32x4 acc2[4][4];
  #pragma unroll
  for (int mi=0;mi<4;mi++)
    #pragma unroll
    for (int ni=0;ni<4;ni++){ f32x4 zv={0.f,0.f,0.f,0.f}; acc2[mi][ni]=zv; }
  #pragma unroll
  for (int k0=0; k0<128; k0+=32){
    bf16x8 ao[4], mj[4];
    #pragma unroll
    for (int mi=0;mi<4;mi++)
      ao[mi] = *(const bf16x8*)&lds[2*JW1 + (wm+mi*16+rl)*128 + ((k0+ksb*8) ^ xr)];
    #pragma unroll
    for (int ni=0;ni<4;ni++)
      mj[ni] = *(const bf16x8*)&lds[(wn+ni*16+rl)*128 + ((k0+ksb*8) ^ xr)];
    #pragma unroll
    for (int ni=0;ni<4;ni++)
      #pragma unroll
      for (int mi=0;mi<4;mi++)
        acc2[mi][ni] = __builtin_amdgcn_mfma_f32_16x16x32_bf16(ao[mi], mj[ni], acc2[mi][ni], 0,0,0);
  }

  const float ws = wsl[k];
  #pragma unroll
  for (int mi=0;mi<4;mi++){
    #pragma unroll
    for (int r=0;r<4;r++){
      const int o = wm + mi*16 + ksb*4 + r;
      const float bo = b2g[k*128 + o];
      #pragma unroll
      for (int ni=0;ni<4;ni++){
        const int j = wn + ni*16 + rl;
        const float v = (acc2[mi][ni][r] + bo) * ws;
        M2T[(size_t)(b*128 + o)*3072 + k*1024 + jt*128 + j] = f2bf(v);
      }
    }
  }
}

// ---------------- pooling + head ----------------
__global__ void pool_kernel(const u16* __restrict__ H, float* __restrict__ pooled){
  const int row = blockIdx.x, t = threadIdx.x;
  u16x4 v = *(const u16x4*)(H + (size_t)row*1024 + t*4);
  float s = bf2f(v.x)+bf2f(v.y)+bf2f(v.z)+bf2f(v.w);
  for (int o2=32;o2>0;o2>>=1) s += __shfl_down(s,o2);
  __shared__ float red[4];
  if ((t&63)==0) red[t>>6]=s;
  __syncthreads();
  if (t==0) pooled[row] = (red[0]+red[1]+red[2]+red[3])*(1.f/1024.f);
}

__global__ void head_kernel(const float* __restrict__ pooled, const float* __restrict__ Wc1,
                            const float* __restrict__ bc1, const float* __restrict__ alpha,
                            const float* __restrict__ Wc2, const float* __restrict__ bc2,
                            float* __restrict__ out){
  const int b = blockIdx.x, h = threadIdx.x;
  __shared__ float p[128], zz[128];
  p[h] = pooled[b*128+h];
  __syncthreads();
  float acc = bc1[h];
  for (int d=0; d<128; d++) acc = fmaf(p[d], Wc1[d*128+h], acc);
  zz[h] = acc>0.f ? acc : alpha[h]*acc;    // PReLU
  __syncthreads();
  if (h<4){
    float a = bc2[h];
    for (int q=0;q<128;q++) a = fmaf(zz[q], Wc2[q*4+h], a);
    out[b*4+h]=a;
  }
}

// ---------------- launcher ----------------
extern "C" void kernel_launch(void* const* d_in, const int* in_sizes, int n_in,
                              void* d_out, int out_size, void* d_ws, size_t ws_size,
                              hipStream_t stream)
{
  const float* x     = (const float*)d_in[0];
  const float* U     = (const float*)d_in[1];
  const float* w1_0  = (const float*)d_in[2];
  const float* b1_0  = (const float*)d_in[3];
  const float* w2_0  = (const float*)d_in[4];
  const float* b2_0  = (const float*)d_in[5];
  const float* w1_r  = (const float*)d_in[6];
  const float* b1_r  = (const float*)d_in[7];
  const float* w2_r  = (const float*)d_in[8];
  const float* b2_r  = (const float*)d_in[9];
  const float* bw    = (const float*)d_in[10];
  const float* Wc1   = (const float*)d_in[11];
  const float* bc1   = (const float*)d_in[12];
  const float* alpha = (const float*)d_in[13];
  const float* Wc2   = (const float*)d_in[14];
  const float* bc2   = (const float*)d_in[15];
  float* out = (float*)d_out;

  char* wsp = (char*)d_ws;
  size_t off = 0;
  auto alloc = [&](size_t bytes) -> void* {
    void* p = wsp + off;
    off = (off + bytes + 255) & ~(size_t)255;
    return p;
  };
  u16* UTcat = (u16*)alloc(6291456);     // [3][1024][1024]
  u16* Ucat  = (u16*)alloc(6291456);     // [1024][3072]
  u16* W1T0  = (u16*)alloc(49152);
  u16* W2T0  = (u16*)alloc(98304);
  u16* W1Tr  = (u16*)alloc(196608);
  u16* W2Tr  = (u16*)alloc(196608);
  float* wsb = (float*)alloc(256);
  u16* HT    = (u16*)alloc(16777216);    // [8192][1024]
  u16* AGG   = (u16*)alloc(50331648);    // AGG2 [(k,b,j)][Din]
  u16* M2T   = (u16*)alloc(50331648);    // [8192][3072]
  float* pooled = (float*)alloc(32768);
  if (off > ws_size) return;

  prep_weights<<<1056, 256, 0, stream>>>(w1_0,w2_0,w1_r,w2_r,bw,
      W1T0,W2T0,W1Tr,W2Tr,wsb);
  prep_U<<<dim3(32,32,3), dim3(32,8), 0, stream>>>(U, UTcat, Ucat);
  prep_x<<<dim3(2,32,64), dim3(32,8), 0, stream>>>(x, HT);

  for (int l=0; l<3; l++){
    const u16* w1t = l ? W1Tr + (size_t)(l-1)*3*16384 : W1T0;
    const u16* w2t = l ? W2Tr + (size_t)(l-1)*3*16384 : W2T0;
    const float* b1 = l ? b1_r + (l-1)*384 : b1_0;
    const float* b2 = l ? b2_r + (l-1)*384 : b2_0;

    // AGG2[((k*64+b)*1024+j)][d] = (U_k^T @ H) row-reordered
    if (l == 0)
      gemm_big<false,6><<<dim3(32, 4, 3), 512, 0, stream>>>(
          UTcat, HT, AGG, 4096, 1024, 1048576L, 0);
    else
      gemm_big<false,7><<<dim3(64, 4, 3), 512, 0, stream>>>(
          UTcat, HT, AGG, 8192, 1024, 1048576L, 0);
    // fused MLP: M2T[(b,o)][(k,j)] = ws_k*(relu(AGG2@W1+b1)@W2 + b2)
    if (l == 0)
      fused_mlp<64><<<dim3(8, 1, 192), 256, 0, stream>>>(
          AGG, w1t, w2t, b1, b2, wsb + l*3, M2T);
    else
      fused_mlp<128><<<dim3(8, 1, 192), 256, 0, stream>>>(
          AGG, w1t, w2t, b1, b2, wsb + l*3, M2T);
    // HT = relu(M2T @ Ucat) : one K=3072 GEMM sums all 3 branches
    gemm_big<true,0><<<dim3(8, 32, 1), 512, 0, stream>>>(
        M2T, Ucat, HT, 1024, 3072, 0L, 0);
  }
  pool_kernel<<<8192, 256, 0, stream>>>(HT, pooled);
  head_kernel<<<64, 128, 0, stream>>>(pooled, Wc1, bc1, alpha, Wc2, bc2, out);
}

// Round 6
// 450.550 us; speedup vs baseline: 1.0597x; 1.0597x over previous
//
#include <hip/hip_runtime.h>

// Graph_CNN_ortega — pure-bf16 MFMA. Big GEMMs (AGG, OUT) on a counted-vmcnt
// ring-3 256x128 kernel, BK=32 (72KB LDS -> 2 blocks/CU), monolithic
// 16-MFMA-per-tile schedule (r3-style; r5's phase split regressed per m196).
// MLP1+MLP2 fused (M1 lives in LDS only). B=64, N=1024, DIN=64, DH=128, L=3.

typedef unsigned short u16;
typedef short bf16x8 __attribute__((ext_vector_type(8)));
typedef float f32x4 __attribute__((ext_vector_type(4)));
typedef u16 u16x4 __attribute__((ext_vector_type(4)));

__device__ __forceinline__ u16 f2bf(float x){
  unsigned u = __builtin_bit_cast(unsigned, x);
  u += 0x7fffu + ((u >> 16) & 1u);          // RNE
  return (u16)(u >> 16);
}
__device__ __forceinline__ float bf2f(u16 h){
  return __builtin_bit_cast(float, ((unsigned)h) << 16);
}
__device__ __forceinline__ void gload16(const u16* g, u16* l){
  __builtin_amdgcn_global_load_lds(
      (const __attribute__((address_space(1))) unsigned int*)(g),
      (__attribute__((address_space(3))) unsigned int*)(l), 16, 0, 0);
}

// ---------------- preprocessing ----------------

__global__ void prep_weights(const float* __restrict__ w1_0, const float* __restrict__ w2_0,
                             const float* __restrict__ w1_r, const float* __restrict__ w2_r,
                             const float* __restrict__ bw,
                             u16* __restrict__ W1T0, u16* __restrict__ W2T0,
                             u16* __restrict__ W1Tr, u16* __restrict__ W2Tr,
                             float* __restrict__ wsb){
  int id = blockIdx.x*256 + threadIdx.x;
  if (id < 3){
    float a0=bw[id*3+0], a1=bw[id*3+1], a2=bw[id*3+2];
    float m = fmaxf(a0,fmaxf(a1,a2));
    float e0=expf(a0-m), e1=expf(a1-m), e2=expf(a2-m);
    float s = e0+e1+e2;
    wsb[id*3+0]=e0/s; wsb[id*3+1]=e1/s; wsb[id*3+2]=e2/s;
  }
  if (id < 24576){                       // W1T0[k][h][d]=w1_0[k][d][h], d<64
    int k=id/8192, rem=id%8192, h=rem/64, d=rem%64;
    W1T0[id] = f2bf(w1_0[(k*64+d)*128 + h]);
  } else if (id < 73728){                // W2T0[k][o][h]=w2_0[k][h][o]
    int t=id-24576, k=t/16384, rem=t%16384, o=rem/128, h=rem%128;
    W2T0[t] = f2bf(w2_0[(k*128+h)*128 + o]);
  } else if (id < 172032){               // W1Tr[lk][h][d]=w1_r[lk][d][h]
    int t=id-73728, lk=t/16384, rem=t%16384, h=rem/128, d=rem%128;
    W1Tr[t] = f2bf(w1_r[lk*16384 + d*128 + h]);
  } else if (id < 270336){               // W2Tr[lk][o][h]=w2_r[lk][h][o]
    int t=id-172032, lk=t/16384, rem=t%16384, o=rem/128, h=rem%128;
    W2Tr[t] = f2bf(w2_r[lk*16384 + h*128 + o]);
  }
}

// U[3][1024][1024] f32 -> UTcat[k][i][j]=U[k][j][i] and Ucat[i][k*1024+j]
__global__ void prep_U(const float* __restrict__ U, u16* __restrict__ UTcat,
                       u16* __restrict__ Ucat){
  __shared__ float t[32][33];
  int k = blockIdx.z, i0 = blockIdx.x*32, j0 = blockIdx.y*32;
  size_t kb = (size_t)k << 20;
  #pragma unroll
  for (int rr=0; rr<4; rr++){
    int r = threadIdx.y*4+rr, c = threadIdx.x;
    float v = U[kb + (size_t)(j0+r)*1024 + i0+c];
    t[r][c] = v;
    Ucat[(size_t)(j0+r)*3072 + k*1024 + i0+c] = f2bf(v);
  }
  __syncthreads();
  #pragma unroll
  for (int rr=0; rr<4; rr++){
    int r = threadIdx.y*4+rr, c = threadIdx.x;
    UTcat[kb + (size_t)(i0+r)*1024 + j0+c] = f2bf(t[c][r]);
  }
}

// x[b][j][d] -> HT0[(b*64+d)][j] bf16
__global__ void prep_x(const float* __restrict__ x, u16* __restrict__ H){
  __shared__ float t[32][33];
  int b = blockIdx.z, d0 = blockIdx.x*32, j0 = blockIdx.y*32;
  #pragma unroll
  for (int rr=0;rr<4;rr++){
    int r=threadIdx.y*4+rr, c=threadIdx.x;
    t[r][c] = x[((size_t)b*1024 + j0+r)*64 + d0+c];
  }
  __syncthreads();
  #pragma unroll
  for (int rr=0;rr<4;rr++){
    int r=threadIdx.y*4+rr, c=threadIdx.x;
    H[(size_t)(b*64 + d0+r)*1024 + j0+c] = f2bf(t[c][r]);
  }
}

// ---------------- big NT GEMM: 256x128 tile, BK=32, ring-3 LDS (72KB ->
// 2 blocks/CU), counted vmcnt(3), one barrier per K-tile. LDS chunk swizzle:
// stored chunk = k ^ ((row>>1)&3) -> 16-lane ds_read_b128 covers all 32 banks
// exactly 2x (free). Source pre-swizzled; gload dest linear (rule #21).
// REORD=0: C[z*cRowZ + m][n].  REORD=p: col n=(b,d), Din=2^p; writes
// C[((z*64+b)*1024+m)][d] (AGG2 row order (k,b,j)).
template<bool RELU, int REORD>
__global__ __launch_bounds__(512, 4)
void gemm_big(const u16* __restrict__ A, const u16* __restrict__ B,
              u16* __restrict__ C, int Nc, int K, long aZ, int cRowZ)
{
  __shared__ __align__(16) u16 ldsA[3*8192];   // 3 x [256][32]  (48 KB)
  __shared__ __align__(16) u16 ldsB[3*4096];   // 3 x [128][32]  (24 KB)
  const int tid = threadIdx.x;
  const int z = blockIdx.z;
  const u16* Ab = A + (size_t)z*aZ;
  const int gx = gridDim.x;
  const int nwg = gx*gridDim.y;
  int flat = blockIdx.y*gx + blockIdx.x;
  if ((nwg & 7) == 0) flat = (flat & 7)*(nwg >> 3) + (flat >> 3);  // T1 XCD swizzle
  const int bm = (flat/gx)*256, bn = (flat%gx)*128;
  const int wave = tid>>6, lane = tid&63;
  const int wm = (wave&3)*64, wn = (wave>>2)*64;
  const int rl = lane&15, ksb = lane>>4;
  const int srow = tid>>2;                         // stage row within 128-row round
  const int scol = ((tid&3)*8) ^ (((tid>>3)&3)<<3); // pre-swizzled source col
  const int NT = K>>5;

  f32x4 acc[4][4];
  #pragma unroll
  for (int mi=0;mi<4;mi++)
    #pragma unroll
    for (int ni=0;ni<4;ni++){ f32x4 zv={0.f,0.f,0.f,0.f}; acc[mi][ni]=zv; }

  auto stage = [&](int t){
    const int sa = (t%3)*8192, sb = (t%3)*4096;
    const int k0 = t<<5;
    #pragma unroll
    for (int c=0;c<2;c++)
      gload16(Ab + (size_t)(bm + c*128 + srow)*K + k0 + scol,
              &ldsA[sa + c*4096 + tid*8]);
    gload16(B + (size_t)(bn + srow)*K + k0 + scol, &ldsB[sb + tid*8]);
  };

  stage(0); stage(1);
  asm volatile("s_waitcnt vmcnt(3)" ::: "memory");   // tile 0 fully landed
  __builtin_amdgcn_s_barrier();
  __builtin_amdgcn_sched_barrier(0);

  for (int t=0; t<NT; t++){
    const int sa = (t%3)*8192, sb = (t%3)*4096;
    bf16x8 af[4], bfr[4];
    #pragma unroll
    for (int mi=0;mi<4;mi++){
      const int row = wm + mi*16 + rl;
      af[mi] = *(const bf16x8*)&ldsA[sa + row*32 + ((ksb*8) ^ (((row>>1)&3)<<3))];
    }
    #pragma unroll
    for (int ni=0;ni<4;ni++){
      const int row = wn + ni*16 + rl;
      bfr[ni] = *(const bf16x8*)&ldsB[sb + row*32 + ((ksb*8) ^ (((row>>1)&3)<<3))];
    }
    if (t+2 < NT) stage(t+2);
    __builtin_amdgcn_s_setprio(1);
    #pragma unroll
    for (int ni=0;ni<4;ni++)
      #pragma unroll
      for (int mi=0;mi<4;mi++)
        acc[mi][ni] = __builtin_amdgcn_mfma_f32_16x16x32_bf16(af[mi], bfr[ni], acc[mi][ni], 0,0,0);
    __builtin_amdgcn_s_setprio(0);
    if (t+2 < NT)      asm volatile("s_waitcnt vmcnt(3)" ::: "memory");
    else if (t+1 < NT) asm volatile("s_waitcnt vmcnt(0)" ::: "memory");
    __builtin_amdgcn_s_barrier();
    __builtin_amdgcn_sched_barrier(0);
  }

  #pragma unroll
  for (int ni=0;ni<4;ni++){
    const int col = bn + wn + ni*16 + rl;
    #pragma unroll
    for (int mi=0;mi<4;mi++){
      const int row0 = bm + wm + mi*16 + ksb*4;          // m89 C layout
      #pragma unroll
      for (int r=0;r<4;r++){
        float v = acc[mi][ni][r];
        if (RELU) v = fmaxf(v, 0.f);
        if constexpr (REORD){
          const int Din = 1 << REORD;
          const int bb = col >> REORD, d = col & (Din-1);
          C[((size_t)((z<<6) + bb)*1024 + row0 + r)*Din + d] = f2bf(v);
        } else {
          C[(size_t)(z*cRowZ + row0 + r)*Nc + col] = f2bf(v);
        }
      }
    }
  }
}

// ---------------- fused MLP: M1 never leaves LDS ----------------
// Block = (k,b,jt): 128 j-rows. stage1: M1=relu(AGG2@W1T^T + b1) -> LDS;
// stage2: M2T[(b,o)][(k,j)] = (W2T@M1^T + b2)*ws_k. All LDS XOR-swizzled
// (elem ^= (row&7)<<3); staged via gload16 with pre-swizzled global source.
template<int DIN>
__global__ __launch_bounds__(256)
void fused_mlp(const u16* __restrict__ AGG, const u16* __restrict__ W1T,
               const u16* __restrict__ W2T, const float* __restrict__ b1g,
               const float* __restrict__ b2g, const float* __restrict__ wsl,
               u16* __restrict__ M2T)
{
  constexpr int JW1 = 128*DIN;                 // elems of lJ / lW1
  __shared__ __align__(16) u16 lds[2*JW1 + 16384]; // lJ | lW1 | lW2 ; lM1 @0
  const int tid = threadIdx.x;
  const int jt = blockIdx.x, z = blockIdx.z, k = z>>6, b = z&63;
  const u16* Ag  = AGG + ((size_t)z*1024 + jt*128)*DIN;
  const u16* W1k = W1T + k*JW1;
  const u16* W2k = W2T + k*16384;
  const int wave = tid>>6, lane = tid&63;
  const int wm = (wave>>1)*64, wn = (wave&1)*64;
  const int rl = lane&15, ksb = lane>>4;
  const int xr = (rl&7)<<3;

  constexpr int CJ = JW1/2048;                 // gload16s per thread (4 or 8)
  #pragma unroll
  for (int c=0;c<CJ;c++){
    const int e = c*2048 + tid*8, row = e/DIN, col = e%DIN;
    gload16(Ag + (size_t)row*DIN + (col ^ ((row&7)<<3)), &lds[e]);
  }
  #pragma unroll
  for (int c=0;c<CJ;c++){
    const int e = c*2048 + tid*8, row = e/DIN, col = e%DIN;
    gload16(W1k + (size_t)row*DIN + (col ^ ((row&7)<<3)), &lds[JW1 + e]);
  }
  #pragma unroll
  for (int c=0;c<8;c++){
    const int e = c*2048 + tid*8, row = e>>7, col = e&127;
    gload16(W2k + (size_t)row*128 + (col ^ ((row&7)<<3)), &lds[2*JW1 + e]);
  }
  asm volatile("s_waitcnt vmcnt(8)" ::: "memory");   // lJ + lW1 landed
  __builtin_amdgcn_s_barrier();
  __builtin_amdgcn_sched_barrier(0);

  // stage 1: C[j][h] = sum_d AGG[j][d]*W1T[h][d]
  f32x4 acc[4][4];
  #pragma unroll
  for (int mi=0;mi<4;mi++)
    #pragma unroll
    for (int ni=0;ni<4;ni++){ f32x4 zv={0.f,0.f,0.f,0.f}; acc[mi][ni]=zv; }
  #pragma unroll
  for (int k0=0; k0<DIN; k0+=32){
    bf16x8 aj[4], wh[4];
    #pragma unroll
    for (int mi=0;mi<4;mi++)
      aj[mi] = *(const bf16x8*)&lds[(wm+mi*16+rl)*DIN + ((k0+ksb*8) ^ xr)];
    #pragma unroll
    for (int ni=0;ni<4;ni++)
      wh[ni] = *(const bf16x8*)&lds[JW1 + (wn+ni*16+rl)*DIN + ((k0+ksb*8) ^ xr)];
    #pragma unroll
    for (int ni=0;ni<4;ni++)
      #pragma unroll
      for (int mi=0;mi<4;mi++)
        acc[mi][ni] = __builtin_amdgcn_mfma_f32_16x16x32_bf16(aj[mi], wh[ni], acc[mi][ni], 0,0,0);
  }
  __syncthreads();                              // lJ/lW1 reads done everywhere

  float bh[4];
  #pragma unroll
  for (int ni=0;ni<4;ni++) bh[ni] = b1g[k*128 + wn + ni*16 + rl];
  #pragma unroll
  for (int ni=0;ni<4;ni++){
    const int h = wn + ni*16 + rl;
    #pragma unroll
    for (int mi=0;mi<4;mi++){
      #pragma unroll
      for (int r=0;r<4;r++){
        const int j = wm + mi*16 + ksb*4 + r;
        const float v = fmaxf(acc[mi][ni][r] + bh[ni], 0.f);
        lds[j*128 + (h ^ ((j&7)<<3))] = f2bf(v);   // lM1 @0
      }
    }
  }
  __syncthreads();                              // M1 visible; lW2 landed

  // stage 2: C2[o][j] = sum_h W2T[o][h]*M1[j][h]
  f32x4 acc2[4][4];
  #pragma unroll
  for (int mi=0;mi<4;mi++)
    #pragma unroll
    for (int ni=0;ni<4;ni++){ f32x4 zv={0.f,0.f,0.f,0.f}; acc2[mi][ni]=zv; }
  #pragma unroll
  for (int k0=0; k0<128; k0+=32){
    bf16x8 ao[4], mj[4];
    #pragma unroll
    for (int mi=0;mi<4;mi++)
      ao[mi] = *(const bf16x8*)&lds[2*JW1 + (wm+mi*16+rl)*128 + ((k0+ksb*8) ^ xr)];
    #pragma unroll
    for (int ni=0;ni<4;ni++)
      mj[ni] = *(const bf16x8*)&lds[(wn+ni*16+rl)*128 + ((k0+ksb*8) ^ xr)];
    #pragma unroll
    for (int ni=0;ni<4;ni++)
      #pragma unroll
      for (int mi=0;mi<4;mi++)
        acc2[mi][ni] = __builtin_amdgcn_mfma_f32_16x16x32_bf16(ao[mi], mj[ni], acc2[mi][ni], 0,0,0);
  }

  const float ws = wsl[k];
  #pragma unroll
  for (int mi=0;mi<4;mi++){
    #pragma unroll
    for (int r=0;r<4;r++){
      const int o = wm + mi*16 + ksb*4 + r;
      const float bo = b2g[k*128 + o];
      #pragma unroll
      for (int ni=0;ni<4;ni++){
        const int j = wn + ni*16 + rl;
        const float v = (acc2[mi][ni][r] + bo) * ws;
        M2T[(size_t)(b*128 + o)*3072 + k*1024 + jt*128 + j] = f2bf(v);
      }
    }
  }
}

// ---------------- pooling + head ----------------
__global__ void pool_kernel(const u16* __restrict__ H, float* __restrict__ pooled){
  const int row = blockIdx.x, t = threadIdx.x;
  u16x4 v = *(const u16x4*)(H + (size_t)row*1024 + t*4);
  float s = bf2f(v.x)+bf2f(v.y)+bf2f(v.z)+bf2f(v.w);
  for (int o2=32;o2>0;o2>>=1) s += __shfl_down(s,o2);
  __shared__ float red[4];
  if ((t&63)==0) red[t>>6]=s;
  __syncthreads();
  if (t==0) pooled[row] = (red[0]+red[1]+red[2]+red[3])*(1.f/1024.f);
}

__global__ void head_kernel(const float* __restrict__ pooled, const float* __restrict__ Wc1,
                            const float* __restrict__ bc1, const float* __restrict__ alpha,
                            const float* __restrict__ Wc2, const float* __restrict__ bc2,
                            float* __restrict__ out){
  const int b = blockIdx.x, h = threadIdx.x;
  __shared__ float p[128], zz[128];
  p[h] = pooled[b*128+h];
  __syncthreads();
  float acc = bc1[h];
  for (int d=0; d<128; d++) acc = fmaf(p[d], Wc1[d*128+h], acc);
  zz[h] = acc>0.f ? acc : alpha[h]*acc;    // PReLU
  __syncthreads();
  if (h<4){
    float a = bc2[h];
    for (int q=0;q<128;q++) a = fmaf(zz[q], Wc2[q*4+h], a);
    out[b*4+h]=a;
  }
}

// ---------------- launcher ----------------
extern "C" void kernel_launch(void* const* d_in, const int* in_sizes, int n_in,
                              void* d_out, int out_size, void* d_ws, size_t ws_size,
                              hipStream_t stream)
{
  const float* x     = (const float*)d_in[0];
  const float* U     = (const float*)d_in[1];
  const float* w1_0  = (const float*)d_in[2];
  const float* b1_0  = (const float*)d_in[3];
  const float* w2_0  = (const float*)d_in[4];
  const float* b2_0  = (const float*)d_in[5];
  const float* w1_r  = (const float*)d_in[6];
  const float* b1_r  = (const float*)d_in[7];
  const float* w2_r  = (const float*)d_in[8];
  const float* b2_r  = (const float*)d_in[9];
  const float* bw    = (const float*)d_in[10];
  const float* Wc1   = (const float*)d_in[11];
  const float* bc1   = (const float*)d_in[12];
  const float* alpha = (const float*)d_in[13];
  const float* Wc2   = (const float*)d_in[14];
  const float* bc2   = (const float*)d_in[15];
  float* out = (float*)d_out;

  char* wsp = (char*)d_ws;
  size_t off = 0;
  auto alloc = [&](size_t bytes) -> void* {
    void* p = wsp + off;
    off = (off + bytes + 255) & ~(size_t)255;
    return p;
  };
  u16* UTcat = (u16*)alloc(6291456);     // [3][1024][1024]
  u16* Ucat  = (u16*)alloc(6291456);     // [1024][3072]
  u16* W1T0  = (u16*)alloc(49152);
  u16* W2T0  = (u16*)alloc(98304);
  u16* W1Tr  = (u16*)alloc(196608);
  u16* W2Tr  = (u16*)alloc(196608);
  float* wsb = (float*)alloc(256);
  u16* HT    = (u16*)alloc(16777216);    // [8192][1024]
  u16* AGG   = (u16*)alloc(50331648);    // AGG2 [(k,b,j)][Din]
  u16* M2T   = (u16*)alloc(50331648);    // [8192][3072]
  float* pooled = (float*)alloc(32768);
  if (off > ws_size) return;

  prep_weights<<<1056, 256, 0, stream>>>(w1_0,w2_0,w1_r,w2_r,bw,
      W1T0,W2T0,W1Tr,W2Tr,wsb);
  prep_U<<<dim3(32,32,3), dim3(32,8), 0, stream>>>(U, UTcat, Ucat);
  prep_x<<<dim3(2,32,64), dim3(32,8), 0, stream>>>(x, HT);

  for (int l=0; l<3; l++){
    const u16* w1t = l ? W1Tr + (size_t)(l-1)*3*16384 : W1T0;
    const u16* w2t = l ? W2Tr + (size_t)(l-1)*3*16384 : W2T0;
    const float* b1 = l ? b1_r + (l-1)*384 : b1_0;
    const float* b2 = l ? b2_r + (l-1)*384 : b2_0;

    // AGG2[((k*64+b)*1024+j)][d] = (U_k^T @ H) row-reordered
    if (l == 0)
      gemm_big<false,6><<<dim3(32, 4, 3), 512, 0, stream>>>(
          UTcat, HT, AGG, 4096, 1024, 1048576L, 0);
    else
      gemm_big<false,7><<<dim3(64, 4, 3), 512, 0, stream>>>(
          UTcat, HT, AGG, 8192, 1024, 1048576L, 0);
    // fused MLP: M2T[(b,o)][(k,j)] = ws_k*(relu(AGG2@W1+b1)@W2 + b2)
    if (l == 0)
      fused_mlp<64><<<dim3(8, 1, 192), 256, 0, stream>>>(
          AGG, w1t, w2t, b1, b2, wsb + l*3, M2T);
    else
      fused_mlp<128><<<dim3(8, 1, 192), 256, 0, stream>>>(
          AGG, w1t, w2t, b1, b2, wsb + l*3, M2T);
    // HT = relu(M2T @ Ucat) : one K=3072 GEMM sums all 3 branches
    gemm_big<true,0><<<dim3(8, 32, 1), 512, 0, stream>>>(
        M2T, Ucat, HT, 1024, 3072, 0L, 0);
  }
  pool_kernel<<<8192, 256, 0, stream>>>(HT, pooled);
  head_kernel<<<64, 128, 0, stream>>>(pooled, Wc1, bc1, alpha, Wc2, bc2, out);
}